// Round 1
// baseline (499.739 us; speedup 1.0000x reference)
//
#include <hip/hip_runtime.h>
#include <hip/hip_bf16.h>

typedef __attribute__((ext_vector_type(8))) short bf16x8;
typedef __attribute__((ext_vector_type(4))) float floatx4;

#define B_ 32
#define S_ 512
#define H_ 512
#define M_ (B_*S_)       // 16384 rows
#define K_ 512
#define N_ 1024          // 2H

// async global->LDS, 16B per lane, LDS dest = wave-uniform base + lane*16
__device__ __forceinline__ void gload_lds16(const void* g, void* l) {
  __builtin_amdgcn_global_load_lds(
      (const __attribute__((address_space(1))) void*)g,
      (__attribute__((address_space(3))) void*)l, 16, 0, 0);
}

// ---------------- fp32 -> bf16 weight convert ----------------
__global__ void cvt_kernel(const float* __restrict__ src,
                           __hip_bfloat16* __restrict__ dst, int n4) {
  int t = blockIdx.x * 256 + threadIdx.x;
  if (t >= n4) return;
  float4 v = *(const float4*)(src + (size_t)t * 4);
  union { ushort4 u; __hip_bfloat16 h[4]; } pk;
  pk.h[0] = __float2bfloat16(v.x);
  pk.h[1] = __float2bfloat16(v.y);
  pk.h[2] = __float2bfloat16(v.z);
  pk.h[3] = __float2bfloat16(v.w);
  *(ushort4*)((unsigned short*)dst + (size_t)t * 4) = pk.u;
}

// ---------------- window conv (both dirs), writes fp32 x and bf16 A ----------------
__global__ void conv_kernel(const float* __restrict__ inf, const float* __restrict__ inb,
                            int instride,
                            const float* __restrict__ fpad, const float* __restrict__ bpad,
                            const float* __restrict__ fw, const float* __restrict__ bw,
                            float* __restrict__ xff, float* __restrict__ xfb,
                            __hip_bfloat16* __restrict__ xaf, __hip_bfloat16* __restrict__ xab) {
  int t = blockIdx.x * 256 + threadIdx.x;      // 0 .. M_*128-1
  int dir = blockIdx.y;
  int row = t >> 7;                            // 0..16383  (= b*S + s)
  int hv  = (t & 127) << 2;                    // h, float4-vectorized
  int s = row & (S_ - 1);
  float4 a = make_float4(0.f, 0.f, 0.f, 0.f);
  if (dir == 0) {
    // f_out[s] = sum_k fw[k] * (s+k<4 ? fpad[s+k] : in[s+k-4])
#pragma unroll
    for (int k = 0; k < 5; ++k) {
      float w = fw[k];
      const float* src = (s + k < 4) ? (fpad + (size_t)(s + k) * H_ + hv)
                                     : (inf + (size_t)(row + k - 4) * instride + hv);
      float4 v = *(const float4*)src;
      a.x += w * v.x; a.y += w * v.y; a.z += w * v.z; a.w += w * v.w;
    }
  } else {
    // b_out[s] = sum_k bw[k] * (s+k<512 ? in[s+k] : bpad[s+k-512])
#pragma unroll
    for (int k = 0; k < 5; ++k) {
      float w = bw[k];
      const float* src = (s + k < S_) ? (inb + (size_t)(row + k) * instride + hv)
                                      : (bpad + (size_t)(s + k - S_) * H_ + hv);
      float4 v = *(const float4*)src;
      a.x += w * v.x; a.y += w * v.y; a.z += w * v.z; a.w += w * v.w;
    }
  }
  float* xf = dir ? xfb : xff;
  __hip_bfloat16* xa = dir ? xab : xaf;
  *(float4*)(xf + (size_t)row * H_ + hv) = a;
  union { ushort4 u; __hip_bfloat16 h[4]; } pk;
  pk.h[0] = __float2bfloat16(a.x);
  pk.h[1] = __float2bfloat16(a.y);
  pk.h[2] = __float2bfloat16(a.z);
  pk.h[3] = __float2bfloat16(a.w);
  *(ushort4*)((unsigned short*)xa + (size_t)row * H_ + hv) = pk.u;
}

// ---------------- fused highway GEMM ----------------
// Block: 128 rows x 64 h-cols; computes proj cols [h0,h0+64) (nonlin) and
// [512+h0, 512+h0+64) (gate), then x_new = g*x + (1-g)*relu(nl).
// A: [M,512] bf16 row-major.  W: [1024,512] bf16 row-major (o-major = B^T layout).
__global__ void hw_gemm(const __hip_bfloat16* __restrict__ Af, const __hip_bfloat16* __restrict__ Ab,
                        const __hip_bfloat16* __restrict__ Wf, const __hip_bfloat16* __restrict__ Wb,
                        const float* __restrict__ biasf, const float* __restrict__ biasb,
                        float* __restrict__ xff, float* __restrict__ xfb,
                        __hip_bfloat16* __restrict__ Anf, __hip_bfloat16* __restrict__ Anb,
                        float* __restrict__ outp, int final_mode) {
  __shared__ __align__(16) __hip_bfloat16 lA[128 * 64];
  __shared__ __align__(16) __hip_bfloat16 lB[128 * 64];

  const int tid = threadIdx.x;
  const int lane = tid & 63, wave = tid >> 6;
  const int wm = wave >> 1, wn = wave & 1;       // wave_m in {0,1}: 64-row half; wave_n: 32-col half
  const int quad = lane >> 4, l16 = lane & 15;
  const int h0 = blockIdx.x * 64;                // h-column tile
  const int m0 = blockIdx.y * 128;               // row tile
  const int dir = blockIdx.z;

  const __hip_bfloat16* A = dir ? Ab : Af;
  const __hip_bfloat16* Wm = dir ? Wb : Wf;
  const float* bias = dir ? biasb : biasf;
  float* xf = dir ? xfb : xff;
  __hip_bfloat16* An = dir ? Anb : Anf;

  floatx4 acc[4][4];   // [m-subtile][j: 0,1=nonlin  2,3=gate]
#pragma unroll
  for (int i = 0; i < 4; ++i)
#pragma unroll
    for (int j = 0; j < 4; ++j) acc[i][j] = (floatx4){0.f, 0.f, 0.f, 0.f};

  const int srow = lane >> 3;          // row within 8-row chunk
  const int skk  = (lane & 7) * 8;     // k element offset (8 bf16 = 16B)

  for (int kp = 0; kp < 8; ++kp) {     // K = 8 * BK(=64)
    const int kb = kp * 64;
    // stage A tile: 128 rows x 64 bf16, row-major in LDS
#pragma unroll
    for (int c = 0; c < 4; ++c) {
      int chunk = wave * 4 + c;                  // 0..15, wave-uniform
      int arow = chunk * 8 + srow;               // 0..127
      gload_lds16(A + (size_t)(m0 + arow) * K_ + kb + skk, &lA[chunk * 512]);
    }
    // stage B tile: rows 0..63 = W[h0+r], rows 64..127 = W[512+h0+r]
#pragma unroll
    for (int c = 0; c < 4; ++c) {
      int chunk = wave * 4 + c;
      int brow = chunk * 8 + srow;
      int wrow = (brow < 64) ? (h0 + brow) : (512 + h0 + brow - 64);
      gload_lds16(Wm + (size_t)wrow * K_ + kb + skk, &lB[chunk * 512]);
    }
    __syncthreads();   // drains vmcnt: global_load_lds complete
#pragma unroll
    for (int ks = 0; ks < 2; ++ks) {
      const int ko = ks * 32 + quad * 8;
      bf16x8 av[4], bv[4];
#pragma unroll
      for (int i = 0; i < 4; ++i)
        av[i] = *(const bf16x8*)&lA[(wm * 64 + i * 16 + l16) * 64 + ko];
#pragma unroll
      for (int j = 0; j < 2; ++j)
        bv[j] = *(const bf16x8*)&lB[(wn * 32 + j * 16 + l16) * 64 + ko];
#pragma unroll
      for (int j = 0; j < 2; ++j)
        bv[2 + j] = *(const bf16x8*)&lB[(64 + wn * 32 + j * 16 + l16) * 64 + ko];
#pragma unroll
      for (int i = 0; i < 4; ++i)
#pragma unroll
        for (int j = 0; j < 4; ++j)
          acc[i][j] = __builtin_amdgcn_mfma_f32_16x16x32_bf16(av[i], bv[j], acc[i][j], 0, 0, 0);
    }
    __syncthreads();
  }

  // epilogue: C/D layout col=lane&15, row=quad*4+reg
  const int cbase = h0 + wn * 32 + l16;
  float bnl[2], bgt[2];
#pragma unroll
  for (int j = 0; j < 2; ++j) {
    bnl[j] = bias[cbase + j * 16];
    bgt[j] = bias[512 + cbase + j * 16];
  }
#pragma unroll
  for (int i = 0; i < 4; ++i) {
    const int rbase = m0 + wm * 64 + i * 16 + quad * 4;
#pragma unroll
    for (int r = 0; r < 4; ++r) {
      const int row = rbase + r;
#pragma unroll
      for (int j = 0; j < 2; ++j) {
        const int c = cbase + j * 16;
        float pn = acc[i][j][r] + bnl[j];
        float pg = acc[i][j + 2][r] + bgt[j];
        float g = 1.f / (1.f + __expf(-pg));
        float xo = xf[(size_t)row * H_ + c];
        float xn = g * xo + (1.f - g) * fmaxf(pn, 0.f);
        if (final_mode) {
          outp[(size_t)row * N_ + dir * H_ + c] = xn;
        } else {
          xf[(size_t)row * H_ + c] = xn;                 // in-place: same thread r/w
          An[(size_t)row * H_ + c] = __float2bfloat16(xn);
        }
      }
    }
  }
}

extern "C" void kernel_launch(void* const* d_in, const int* in_sizes, int n_in,
                              void* d_out, int out_size, void* d_ws, size_t ws_size,
                              hipStream_t stream) {
  const float* inputs   = (const float*)d_in[0];
  // d_in[1] = masks (unused by reference)
  const float* fwd_pads = (const float*)d_in[2];
  const float* bwd_pads = (const float*)d_in[3];
  const float* fwd_ws_p = (const float*)d_in[4];
  const float* bwd_ws_p = (const float*)d_in[5];
  const float* fwd_hw_W = (const float*)d_in[6];
  const float* fwd_hw_b = (const float*)d_in[7];
  const float* bwd_hw_W = (const float*)d_in[8];
  const float* bwd_hw_b = (const float*)d_in[9];
  float* out = (float*)d_out;

  char* ws = (char*)d_ws;
  size_t off = 0;
  __hip_bfloat16* Wbf = (__hip_bfloat16*)(ws + off); off += (size_t)4194304 * 2;  // 8 matrices [1024,512]
  float* xff = (float*)(ws + off); off += (size_t)M_ * H_ * 4;
  float* xfb = (float*)(ws + off); off += (size_t)M_ * H_ * 4;
  __hip_bfloat16* xa0f = (__hip_bfloat16*)(ws + off); off += (size_t)M_ * H_ * 2;
  __hip_bfloat16* xa0b = (__hip_bfloat16*)(ws + off); off += (size_t)M_ * H_ * 2;
  __hip_bfloat16* xa1f = (__hip_bfloat16*)(ws + off); off += (size_t)M_ * H_ * 2;
  __hip_bfloat16* xa1b = (__hip_bfloat16*)(ws + off); off += (size_t)M_ * H_ * 2;
  // total ~136 MiB

  // weights -> bf16 (fwd at 0, bwd at +2097152 elements)
  cvt_kernel<<<2048, 256, 0, stream>>>(fwd_hw_W, Wbf, 524288);
  cvt_kernel<<<2048, 256, 0, stream>>>(bwd_hw_W, Wbf + (size_t)2097152, 524288);

  for (int l = 0; l < 2; ++l) {
    const float *inf, *inb;
    int instride;
    if (l == 0) { inf = inputs; inb = inputs; instride = H_; }
    else        { inf = out;    inb = out + H_; instride = N_; }  // read layer-0 output
    conv_kernel<<<dim3(8192, 2), 256, 0, stream>>>(
        inf, inb, instride,
        fwd_pads + (size_t)l * 4 * H_, bwd_pads + (size_t)l * 4 * H_,
        fwd_ws_p + l * 5, bwd_ws_p + l * 5,
        xff, xfb, xa0f, xa0b);

    // highway iter 0 (writes fp32 x in-place + bf16 A ping)
    hw_gemm<<<dim3(8, 128, 2), 256, 0, stream>>>(
        xa0f, xa0b,
        Wbf + (size_t)(l * 2) * 524288, Wbf + (size_t)2097152 + (size_t)(l * 2) * 524288,
        fwd_hw_b + (l * 2) * 1024, bwd_hw_b + (l * 2) * 1024,
        xff, xfb, xa1f, xa1b, nullptr, 0);

    // highway iter 1 (final: writes d_out[l])
    hw_gemm<<<dim3(8, 128, 2), 256, 0, stream>>>(
        xa1f, xa1b,
        Wbf + (size_t)(l * 2 + 1) * 524288, Wbf + (size_t)2097152 + (size_t)(l * 2 + 1) * 524288,
        fwd_hw_b + (l * 2 + 1) * 1024, bwd_hw_b + (l * 2 + 1) * 1024,
        xff, xfb, nullptr, nullptr, out + (size_t)l * M_ * N_, 1);
  }
}

// Round 2
// 479.600 us; speedup vs baseline: 1.0420x; 1.0420x over previous
//
#include <hip/hip_runtime.h>
#include <hip/hip_bf16.h>

typedef __attribute__((ext_vector_type(8))) short bf16x8;
typedef __attribute__((ext_vector_type(4))) float floatx4;

#define B_ 32
#define S_ 512
#define H_ 512
#define M_ (B_*S_)       // 16384 rows
#define K_ 512
#define N_ 1024          // 2H

// async global->LDS, 16B per lane, LDS dest = wave-uniform base + lane*16
__device__ __forceinline__ void gload_lds16(const void* g, void* l) {
  __builtin_amdgcn_global_load_lds(
      (const __attribute__((address_space(1))) void*)g,
      (__attribute__((address_space(3))) void*)l, 16, 0, 0);
}

// ---------------- fp32 -> bf16 weight convert ----------------
__global__ void cvt_kernel(const float* __restrict__ src,
                           __hip_bfloat16* __restrict__ dst, int n4) {
  int t = blockIdx.x * 256 + threadIdx.x;
  if (t >= n4) return;
  float4 v = *(const float4*)(src + (size_t)t * 4);
  union { ushort4 u; __hip_bfloat16 h[4]; } pk;
  pk.h[0] = __float2bfloat16(v.x);
  pk.h[1] = __float2bfloat16(v.y);
  pk.h[2] = __float2bfloat16(v.z);
  pk.h[3] = __float2bfloat16(v.w);
  *(ushort4*)((unsigned short*)dst + (size_t)t * 4) = pk.u;
}

// ---------------- window conv (both dirs), writes bf16 x only ----------------
__global__ void conv_kernel(const float* __restrict__ inf, const float* __restrict__ inb,
                            int instride,
                            const float* __restrict__ fpad, const float* __restrict__ bpad,
                            const float* __restrict__ fw, const float* __restrict__ bw,
                            __hip_bfloat16* __restrict__ xaf, __hip_bfloat16* __restrict__ xab) {
  int t = blockIdx.x * 256 + threadIdx.x;      // 0 .. M_*128-1
  int dir = blockIdx.y;
  int row = t >> 7;                            // 0..16383  (= b*S + s)
  int hv  = (t & 127) << 2;                    // h, float4-vectorized
  int s = row & (S_ - 1);
  float4 a = make_float4(0.f, 0.f, 0.f, 0.f);
  if (dir == 0) {
    // f_out[s] = sum_k fw[k] * (s+k<4 ? fpad[s+k] : in[s+k-4])
#pragma unroll
    for (int k = 0; k < 5; ++k) {
      float w = fw[k];
      const float* src = (s + k < 4) ? (fpad + (size_t)(s + k) * H_ + hv)
                                     : (inf + (size_t)(row + k - 4) * instride + hv);
      float4 v = *(const float4*)src;
      a.x += w * v.x; a.y += w * v.y; a.z += w * v.z; a.w += w * v.w;
    }
  } else {
    // b_out[s] = sum_k bw[k] * (s+k<512 ? in[s+k] : bpad[s+k-512])
#pragma unroll
    for (int k = 0; k < 5; ++k) {
      float w = bw[k];
      const float* src = (s + k < S_) ? (inb + (size_t)(row + k) * instride + hv)
                                      : (bpad + (size_t)(s + k - S_) * H_ + hv);
      float4 v = *(const float4*)src;
      a.x += w * v.x; a.y += w * v.y; a.z += w * v.z; a.w += w * v.w;
    }
  }
  __hip_bfloat16* xa = dir ? xab : xaf;
  union { ushort4 u; __hip_bfloat16 h[4]; } pk;
  pk.h[0] = __float2bfloat16(a.x);
  pk.h[1] = __float2bfloat16(a.y);
  pk.h[2] = __float2bfloat16(a.z);
  pk.h[3] = __float2bfloat16(a.w);
  *(ushort4*)((unsigned short*)xa + (size_t)row * H_ + hv) = pk.u;
}

// ---------------- fused highway GEMM ----------------
// Block: 128 rows x 64 h-cols; computes proj cols [h0,h0+64) (nonlin) and
// [512+h0, 512+h0+64) (gate), then x_new = g*x + (1-g)*relu(nl).
// A: [M,512] bf16 row-major (doubles as residual x).
// W: [1024,512] bf16 row-major (o-major = B^T layout).
// Residual x_old is snapshotted from the LDS A-tile at kp == h0/64 — no
// global re-read of x in the epilogue.
__global__ void hw_gemm(const __hip_bfloat16* __restrict__ Af, const __hip_bfloat16* __restrict__ Ab,
                        const __hip_bfloat16* __restrict__ Wf, const __hip_bfloat16* __restrict__ Wb,
                        const float* __restrict__ biasf, const float* __restrict__ biasb,
                        __hip_bfloat16* __restrict__ Anf, __hip_bfloat16* __restrict__ Anb,
                        float* __restrict__ outp, int final_mode) {
  __shared__ __align__(16) __hip_bfloat16 lA[128 * 64];
  __shared__ __align__(16) __hip_bfloat16 lB[128 * 64];

  const int tid = threadIdx.x;
  const int lane = tid & 63, wave = tid >> 6;
  const int wm = wave >> 1, wn = wave & 1;       // wave_m in {0,1}: 64-row half; wave_n: 32-col half
  const int quad = lane >> 4, l16 = lane & 15;
  const int h0 = blockIdx.x * 64;                // h-column tile
  const int m0 = blockIdx.y * 128;               // row tile
  const int dir = blockIdx.z;

  const __hip_bfloat16* A = dir ? Ab : Af;
  const __hip_bfloat16* Wm = dir ? Wb : Wf;
  const float* bias = dir ? biasb : biasf;
  __hip_bfloat16* An = dir ? Anb : Anf;

  floatx4 acc[4][4];   // [m-subtile][j: 0,1=nonlin  2,3=gate]
#pragma unroll
  for (int i = 0; i < 4; ++i)
#pragma unroll
    for (int j = 0; j < 4; ++j) acc[i][j] = (floatx4){0.f, 0.f, 0.f, 0.f};

  float xs[4][2][4];   // residual snapshot [i][j][r]

  const int srow = lane >> 3;          // row within 8-row chunk
  const int skk  = (lane & 7) * 8;     // k element offset (8 bf16 = 16B)
  const int xkp = h0 >> 6;             // kp at which lA holds x cols [h0,h0+64)

  for (int kp = 0; kp < 8; ++kp) {     // K = 8 * BK(=64)
    const int kb = kp * 64;
    // stage A tile: 128 rows x 64 bf16, row-major in LDS
#pragma unroll
    for (int c = 0; c < 4; ++c) {
      int chunk = wave * 4 + c;                  // 0..15, wave-uniform
      int arow = chunk * 8 + srow;               // 0..127
      gload_lds16(A + (size_t)(m0 + arow) * K_ + kb + skk, &lA[chunk * 512]);
    }
    // stage B tile: rows 0..63 = W[h0+r], rows 64..127 = W[512+h0+r]
#pragma unroll
    for (int c = 0; c < 4; ++c) {
      int chunk = wave * 4 + c;
      int brow = chunk * 8 + srow;
      int wrow = (brow < 64) ? (h0 + brow) : (512 + h0 + brow - 64);
      gload_lds16(Wm + (size_t)wrow * K_ + kb + skk, &lB[chunk * 512]);
    }
    __syncthreads();   // drains vmcnt: global_load_lds complete

    if (kp == xkp) {
      // snapshot residual x for the epilogue from the staged A-tile
#pragma unroll
      for (int i = 0; i < 4; ++i)
#pragma unroll
        for (int j = 0; j < 2; ++j)
#pragma unroll
          for (int r = 0; r < 4; ++r)
            xs[i][j][r] = __bfloat162float(
                lA[(wm * 64 + i * 16 + quad * 4 + r) * 64 + wn * 32 + j * 16 + l16]);
    }

#pragma unroll
    for (int ks = 0; ks < 2; ++ks) {
      const int ko = ks * 32 + quad * 8;
      bf16x8 av[4], bv[4];
#pragma unroll
      for (int i = 0; i < 4; ++i)
        av[i] = *(const bf16x8*)&lA[(wm * 64 + i * 16 + l16) * 64 + ko];
#pragma unroll
      for (int j = 0; j < 2; ++j)
        bv[j] = *(const bf16x8*)&lB[(wn * 32 + j * 16 + l16) * 64 + ko];
#pragma unroll
      for (int j = 0; j < 2; ++j)
        bv[2 + j] = *(const bf16x8*)&lB[(64 + wn * 32 + j * 16 + l16) * 64 + ko];
#pragma unroll
      for (int i = 0; i < 4; ++i)
#pragma unroll
        for (int j = 0; j < 4; ++j)
          acc[i][j] = __builtin_amdgcn_mfma_f32_16x16x32_bf16(av[i], bv[j], acc[i][j], 0, 0, 0);
    }
    __syncthreads();
  }

  // epilogue: C/D layout col=lane&15, row=quad*4+reg
  const int cbase = h0 + wn * 32 + l16;
  float bnl[2], bgt[2];
#pragma unroll
  for (int j = 0; j < 2; ++j) {
    bnl[j] = bias[cbase + j * 16];
    bgt[j] = bias[512 + cbase + j * 16];
  }
#pragma unroll
  for (int i = 0; i < 4; ++i) {
    const int rbase = m0 + wm * 64 + i * 16 + quad * 4;
#pragma unroll
    for (int r = 0; r < 4; ++r) {
      const int row = rbase + r;
#pragma unroll
      for (int j = 0; j < 2; ++j) {
        const int c = cbase + j * 16;
        float pn = acc[i][j][r] + bnl[j];
        float pg = acc[i][j + 2][r] + bgt[j];
        float g = 1.f / (1.f + __expf(-pg));
        float xo = xs[i][j][r];
        float xn = g * xo + (1.f - g) * fmaxf(pn, 0.f);
        if (final_mode) {
          outp[(size_t)row * N_ + dir * H_ + c] = xn;
        } else {
          An[(size_t)row * H_ + c] = __float2bfloat16(xn);
        }
      }
    }
  }
}

extern "C" void kernel_launch(void* const* d_in, const int* in_sizes, int n_in,
                              void* d_out, int out_size, void* d_ws, size_t ws_size,
                              hipStream_t stream) {
  const float* inputs   = (const float*)d_in[0];
  // d_in[1] = masks (unused by reference)
  const float* fwd_pads = (const float*)d_in[2];
  const float* bwd_pads = (const float*)d_in[3];
  const float* fwd_ws_p = (const float*)d_in[4];
  const float* bwd_ws_p = (const float*)d_in[5];
  const float* fwd_hw_W = (const float*)d_in[6];
  const float* fwd_hw_b = (const float*)d_in[7];
  const float* bwd_hw_W = (const float*)d_in[8];
  const float* bwd_hw_b = (const float*)d_in[9];
  float* out = (float*)d_out;

  char* ws = (char*)d_ws;
  size_t off = 0;
  __hip_bfloat16* Wbf = (__hip_bfloat16*)(ws + off); off += (size_t)4194304 * 2;  // 8 matrices [1024,512]
  __hip_bfloat16* xa0f = (__hip_bfloat16*)(ws + off); off += (size_t)M_ * H_ * 2;
  __hip_bfloat16* xa0b = (__hip_bfloat16*)(ws + off); off += (size_t)M_ * H_ * 2;
  __hip_bfloat16* xa1f = (__hip_bfloat16*)(ws + off); off += (size_t)M_ * H_ * 2;
  __hip_bfloat16* xa1b = (__hip_bfloat16*)(ws + off); off += (size_t)M_ * H_ * 2;
  // total ~75 MiB

  // weights -> bf16 (fwd at 0, bwd at +2097152 elements)
  cvt_kernel<<<2048, 256, 0, stream>>>(fwd_hw_W, Wbf, 524288);
  cvt_kernel<<<2048, 256, 0, stream>>>(bwd_hw_W, Wbf + (size_t)2097152, 524288);

  for (int l = 0; l < 2; ++l) {
    const float *inf, *inb;
    int instride;
    if (l == 0) { inf = inputs; inb = inputs; instride = H_; }
    else        { inf = out;    inb = out + H_; instride = N_; }  // read layer-0 output
    conv_kernel<<<dim3(8192, 2), 256, 0, stream>>>(
        inf, inb, instride,
        fwd_pads + (size_t)l * 4 * H_, bwd_pads + (size_t)l * 4 * H_,
        fwd_ws_p + l * 5, bwd_ws_p + l * 5,
        xa0f, xa0b);

    // highway iter 0 (writes bf16 x ping)
    hw_gemm<<<dim3(8, 128, 2), 256, 0, stream>>>(
        xa0f, xa0b,
        Wbf + (size_t)(l * 2) * 524288, Wbf + (size_t)2097152 + (size_t)(l * 2) * 524288,
        fwd_hw_b + (l * 2) * 1024, bwd_hw_b + (l * 2) * 1024,
        xa1f, xa1b, nullptr, 0);

    // highway iter 1 (final: writes d_out[l])
    hw_gemm<<<dim3(8, 128, 2), 256, 0, stream>>>(
        xa1f, xa1b,
        Wbf + (size_t)(l * 2 + 1) * 524288, Wbf + (size_t)2097152 + (size_t)(l * 2 + 1) * 524288,
        fwd_hw_b + (l * 2 + 1) * 1024, bwd_hw_b + (l * 2 + 1) * 1024,
        nullptr, nullptr, out + (size_t)l * M_ * N_, 1);
  }
}

// Round 3
// 474.306 us; speedup vs baseline: 1.0536x; 1.0112x over previous
//
#include <hip/hip_runtime.h>
#include <hip/hip_bf16.h>

typedef __attribute__((ext_vector_type(8))) short bf16x8;
typedef __attribute__((ext_vector_type(4))) float floatx4;

#define B_ 32
#define S_ 512
#define H_ 512
#define M_ (B_*S_)       // 16384 rows
#define K_ 512
#define N_ 1024          // 2H

// async global->LDS, 16B per lane, LDS dest = wave-uniform base + lane*16
__device__ __forceinline__ void gload_lds16(const void* g, void* l) {
  __builtin_amdgcn_global_load_lds(
      (const __attribute__((address_space(1))) void*)g,
      (__attribute__((address_space(3))) void*)l, 16, 0, 0);
}

// ---------------- fp32 -> bf16 weight convert ----------------
__global__ void cvt_kernel(const float* __restrict__ src,
                           __hip_bfloat16* __restrict__ dst, int n4) {
  int t = blockIdx.x * 256 + threadIdx.x;
  if (t >= n4) return;
  float4 v = *(const float4*)(src + (size_t)t * 4);
  union { ushort4 u; __hip_bfloat16 h[4]; } pk;
  pk.h[0] = __float2bfloat16(v.x);
  pk.h[1] = __float2bfloat16(v.y);
  pk.h[2] = __float2bfloat16(v.z);
  pk.h[3] = __float2bfloat16(v.w);
  *(ushort4*)((unsigned short*)dst + (size_t)t * 4) = pk.u;
}

// ---------------- window conv (both dirs), writes bf16 x only ----------------
__global__ void conv_kernel(const float* __restrict__ inf, const float* __restrict__ inb,
                            int instride,
                            const float* __restrict__ fpad, const float* __restrict__ bpad,
                            const float* __restrict__ fw, const float* __restrict__ bw,
                            __hip_bfloat16* __restrict__ xaf, __hip_bfloat16* __restrict__ xab) {
  int t = blockIdx.x * 256 + threadIdx.x;      // 0 .. M_*128-1
  int dir = blockIdx.y;
  int row = t >> 7;                            // 0..16383  (= b*S + s)
  int hv  = (t & 127) << 2;                    // h, float4-vectorized
  int s = row & (S_ - 1);
  float4 a = make_float4(0.f, 0.f, 0.f, 0.f);
  if (dir == 0) {
#pragma unroll
    for (int k = 0; k < 5; ++k) {
      float w = fw[k];
      const float* src = (s + k < 4) ? (fpad + (size_t)(s + k) * H_ + hv)
                                     : (inf + (size_t)(row + k - 4) * instride + hv);
      float4 v = *(const float4*)src;
      a.x += w * v.x; a.y += w * v.y; a.z += w * v.z; a.w += w * v.w;
    }
  } else {
#pragma unroll
    for (int k = 0; k < 5; ++k) {
      float w = bw[k];
      const float* src = (s + k < S_) ? (inb + (size_t)(row + k) * instride + hv)
                                      : (bpad + (size_t)(s + k - S_) * H_ + hv);
      float4 v = *(const float4*)src;
      a.x += w * v.x; a.y += w * v.y; a.z += w * v.z; a.w += w * v.w;
    }
  }
  __hip_bfloat16* xa = dir ? xab : xaf;
  union { ushort4 u; __hip_bfloat16 h[4]; } pk;
  pk.h[0] = __float2bfloat16(a.x);
  pk.h[1] = __float2bfloat16(a.y);
  pk.h[2] = __float2bfloat16(a.z);
  pk.h[3] = __float2bfloat16(a.w);
  *(ushort4*)((unsigned short*)xa + (size_t)row * H_ + hv) = pk.u;
}

// ---------------- fused highway GEMM ----------------
// Block: 128 rows x 64 h-cols -> proj cols [h0,h0+64) (nonlin) + [512+h0,..) (gate),
// then x_new = g*x + (1-g)*relu(nl).  A:[M,512] bf16 rm (doubles as residual x).
// W:[1024,512] bf16 rm.  LDS is XOR-swizzled: LDS(row, cc) holds global k-chunk
// cc ^ (row&7) (16B chunks), achieved by permuting the k-offset each staging lane
// FETCHES (global_load_lds's LDS dest is fixed at base+lane*16).
// XCD-aware remap: the 8 h-sibling blocks of one A-panel land on one XCD.
__global__ void hw_gemm(const __hip_bfloat16* __restrict__ Af, const __hip_bfloat16* __restrict__ Ab,
                        const __hip_bfloat16* __restrict__ Wf, const __hip_bfloat16* __restrict__ Wb,
                        const float* __restrict__ biasf, const float* __restrict__ biasb,
                        __hip_bfloat16* __restrict__ Anf, __hip_bfloat16* __restrict__ Anb,
                        float* __restrict__ outp, int final_mode) {
  __shared__ __align__(16) __hip_bfloat16 lA[128 * 64];
  __shared__ __align__(16) __hip_bfloat16 lB[128 * 64];

  const int tid = threadIdx.x;
  const int lane = tid & 63, wave = tid >> 6;
  const int wm = wave >> 1, wn = wave & 1;
  const int quad = lane >> 4, l16 = lane & 15;
  const int dir = blockIdx.z;

  // XCD-aware remap (x-fastest dispatch; round-robin block->XCD assumed; perf-only)
  const int n = blockIdx.y * 8 + blockIdx.x;   // [0,1024) within dir
  const int xcd = n & 7;
  const int h0 = ((n >> 3) & 7) * 64;
  const int m0 = (xcd + (n >> 6) * 8) * 128;

  const __hip_bfloat16* A = dir ? Ab : Af;
  const __hip_bfloat16* Wm = dir ? Wb : Wf;
  const float* bias = dir ? biasb : biasf;
  __hip_bfloat16* An = dir ? Anb : Anf;

  floatx4 acc[4][4];   // [m-subtile][j: 0,1=nonlin  2,3=gate]
#pragma unroll
  for (int i = 0; i < 4; ++i)
#pragma unroll
    for (int j = 0; j < 4; ++j) acc[i][j] = (floatx4){0.f, 0.f, 0.f, 0.f};

  float xs[4][2][4];   // residual snapshot [i][j][r]

  const int srow = lane >> 3;                    // row within 8-row chunk
  const int skk  = (((lane & 7) ^ srow) << 3);   // SWIZZLED k element offset
  const int xkp  = h0 >> 6;                      // kp at which lA holds x cols [h0,h0+64)
  const int sw   = l16 & 7;                      // read-side swizzle key (= row&7)

  // hoisted staging base pointers
  const __hip_bfloat16* aptr[4];
  const __hip_bfloat16* bptr[4];
#pragma unroll
  for (int c = 0; c < 4; ++c) {
    const int chunk = wave * 4 + c;
    const int arow = chunk * 8 + srow;
    aptr[c] = A + (size_t)(m0 + arow) * K_ + skk;
    const int brow = chunk * 8 + srow;
    const int wrow = (brow < 64) ? (h0 + brow) : (512 + h0 + brow - 64);
    bptr[c] = Wm + (size_t)wrow * K_ + skk;
  }

  for (int kp = 0; kp < 8; ++kp) {     // K = 8 * BK(=64)
    const int kb = kp * 64;
#pragma unroll
    for (int c = 0; c < 4; ++c) {
      const int chunk = wave * 4 + c;
      gload_lds16(aptr[c] + kb, &lA[chunk * 512]);
      gload_lds16(bptr[c] + kb, &lB[chunk * 512]);
    }
    __syncthreads();   // drains vmcnt: global_load_lds complete

    if (kp == xkp) {
      // snapshot residual x for the epilogue from the staged (swizzled) A-tile
#pragma unroll
      for (int i = 0; i < 4; ++i)
#pragma unroll
        for (int j = 0; j < 2; ++j)
#pragma unroll
          for (int r = 0; r < 4; ++r) {
            const int ra = wm * 64 + i * 16 + quad * 4 + r;
            const int c2 = wn * 32 + j * 16 + l16;
            xs[i][j][r] = __bfloat162float(
                lA[ra * 64 + ((((c2 >> 3) ^ (ra & 7)) << 3) | (c2 & 7))]);
          }
    }

#pragma unroll
    for (int ks = 0; ks < 2; ++ks) {
      bf16x8 av[4], bv[4];
#pragma unroll
      for (int i = 0; i < 4; ++i) {
        const int ra = wm * 64 + i * 16 + l16;
        av[i] = *(const bf16x8*)&lA[ra * 64 + (((ks * 4 + quad) ^ sw) << 3)];
      }
#pragma unroll
      for (int j = 0; j < 2; ++j) {
        const int rb = wn * 32 + j * 16 + l16;
        bv[j] = *(const bf16x8*)&lB[rb * 64 + (((ks * 4 + quad) ^ sw) << 3)];
      }
#pragma unroll
      for (int j = 0; j < 2; ++j) {
        const int rb = 64 + wn * 32 + j * 16 + l16;
        bv[2 + j] = *(const bf16x8*)&lB[rb * 64 + (((ks * 4 + quad) ^ sw) << 3)];
      }
#pragma unroll
      for (int i = 0; i < 4; ++i)
#pragma unroll
        for (int j = 0; j < 4; ++j)
          acc[i][j] = __builtin_amdgcn_mfma_f32_16x16x32_bf16(av[i], bv[j], acc[i][j], 0, 0, 0);
    }
    __syncthreads();
  }

  // epilogue: C/D layout col=lane&15, row=quad*4+reg
  const int cbase = h0 + wn * 32 + l16;
  float bnl[2], bgt[2];
#pragma unroll
  for (int j = 0; j < 2; ++j) {
    bnl[j] = bias[cbase + j * 16];
    bgt[j] = bias[512 + cbase + j * 16];
  }
#pragma unroll
  for (int i = 0; i < 4; ++i) {
    const int rbase = m0 + wm * 64 + i * 16 + quad * 4;
#pragma unroll
    for (int r = 0; r < 4; ++r) {
      const int row = rbase + r;
#pragma unroll
      for (int j = 0; j < 2; ++j) {
        const int c = cbase + j * 16;
        float pn = acc[i][j][r] + bnl[j];
        float pg = acc[i][j + 2][r] + bgt[j];
        float g = 1.f / (1.f + __expf(-pg));
        float xo = xs[i][j][r];
        float xn = g * xo + (1.f - g) * fmaxf(pn, 0.f);
        if (final_mode) {
          outp[(size_t)row * N_ + dir * H_ + c] = xn;
        } else {
          An[(size_t)row * H_ + c] = __float2bfloat16(xn);
        }
      }
    }
  }
}

extern "C" void kernel_launch(void* const* d_in, const int* in_sizes, int n_in,
                              void* d_out, int out_size, void* d_ws, size_t ws_size,
                              hipStream_t stream) {
  const float* inputs   = (const float*)d_in[0];
  // d_in[1] = masks (unused by reference)
  const float* fwd_pads = (const float*)d_in[2];
  const float* bwd_pads = (const float*)d_in[3];
  const float* fwd_ws_p = (const float*)d_in[4];
  const float* bwd_ws_p = (const float*)d_in[5];
  const float* fwd_hw_W = (const float*)d_in[6];
  const float* fwd_hw_b = (const float*)d_in[7];
  const float* bwd_hw_W = (const float*)d_in[8];
  const float* bwd_hw_b = (const float*)d_in[9];
  float* out = (float*)d_out;

  char* ws = (char*)d_ws;
  size_t off = 0;
  __hip_bfloat16* Wbf = (__hip_bfloat16*)(ws + off); off += (size_t)4194304 * 2;  // 8 matrices [1024,512]
  __hip_bfloat16* xa0f = (__hip_bfloat16*)(ws + off); off += (size_t)M_ * H_ * 2;
  __hip_bfloat16* xa0b = (__hip_bfloat16*)(ws + off); off += (size_t)M_ * H_ * 2;
  __hip_bfloat16* xa1f = (__hip_bfloat16*)(ws + off); off += (size_t)M_ * H_ * 2;
  __hip_bfloat16* xa1b = (__hip_bfloat16*)(ws + off); off += (size_t)M_ * H_ * 2;
  // total ~75 MiB

  // weights -> bf16 (fwd at 0, bwd at +2097152 elements)
  cvt_kernel<<<2048, 256, 0, stream>>>(fwd_hw_W, Wbf, 524288);
  cvt_kernel<<<2048, 256, 0, stream>>>(bwd_hw_W, Wbf + (size_t)2097152, 524288);

  for (int l = 0; l < 2; ++l) {
    const float *inf, *inb;
    int instride;
    if (l == 0) { inf = inputs; inb = inputs; instride = H_; }
    else        { inf = out;    inb = out + H_; instride = N_; }  // read layer-0 output
    conv_kernel<<<dim3(8192, 2), 256, 0, stream>>>(
        inf, inb, instride,
        fwd_pads + (size_t)l * 4 * H_, bwd_pads + (size_t)l * 4 * H_,
        fwd_ws_p + l * 5, bwd_ws_p + l * 5,
        xa0f, xa0b);

    // highway iter 0 (writes bf16 x ping)
    hw_gemm<<<dim3(8, 128, 2), 256, 0, stream>>>(
        xa0f, xa0b,
        Wbf + (size_t)(l * 2) * 524288, Wbf + (size_t)2097152 + (size_t)(l * 2) * 524288,
        fwd_hw_b + (l * 2) * 1024, bwd_hw_b + (l * 2) * 1024,
        xa1f, xa1b, nullptr, 0);

    // highway iter 1 (final: writes d_out[l])
    hw_gemm<<<dim3(8, 128, 2), 256, 0, stream>>>(
        xa1f, xa1b,
        Wbf + (size_t)(l * 2 + 1) * 524288, Wbf + (size_t)2097152 + (size_t)(l * 2 + 1) * 524288,
        fwd_hw_b + (l * 2 + 1) * 1024, bwd_hw_b + (l * 2 + 1) * 1024,
        nullptr, nullptr, out + (size_t)l * M_ * N_, 1);
  }
}